// Round 3
// baseline (921.512 us; speedup 1.0000x reference)
//
#include <hip/hip_runtime.h>
#include <stdint.h>

#define BB 16
#define TT 4096
#define CC 8
#define FF 64
#define KW 11
#define LL 4096

// ---------------- Kernel 1: conv1d + BN + exp -> sumexp[b,f] (no h storage) -------
__global__ __launch_bounds__(256) void k_sumexp(
        const float* __restrict__ x, const float* __restrict__ cw,
        const float* __restrict__ cb, const float* __restrict__ gm,
        const float* __restrict__ bt, const float* __restrict__ mn,
        const float* __restrict__ vr, float* __restrict__ sumexp) {
    __shared__ float wsm[KW * CC * FF];       // 5632 floats
    __shared__ float xs[(64 + KW - 1) * CC];  // 592 floats
    __shared__ float red[4 * FF];
    const int tid = threadIdx.x;
    const int b  = blockIdx.x / (TT / 64);
    const int t0 = (blockIdx.x % (TT / 64)) * 64;

    for (int i = tid; i < KW * CC * FF; i += 256) wsm[i] = cw[i];
    for (int i = tid; i < (64 + KW - 1) * CC; i += 256) {
        int row = i / CC, c = i % CC;
        int t = t0 - (KW / 2) + row;
        xs[i] = (t >= 0 && t < TT) ? x[((size_t)b * TT + t) * CC + c] : 0.0f;
    }
    const int f = tid & 63, ts = tid >> 6;
    const float s  = gm[f] * rsqrtf(vr[f] + 1e-3f);
    const float bb = bt[f] + (cb[f] - mn[f]) * s;
    __syncthreads();

    float esum = 0.f;
    for (int tt = ts; tt < 64; tt += 4) {
        float acc = 0.f;
#pragma unroll
        for (int k = 0; k < KW; ++k) {
#pragma unroll
            for (int c = 0; c < CC; ++c)
                acc = fmaf(xs[(tt + k) * CC + c], wsm[(k * CC + c) * FF + f], acc);
        }
        esum += __expf(fmaf(acc, s, bb));
    }
    red[ts * FF + f] = esum;
    __syncthreads();
    if (ts == 0) {
        float tot = red[f] + red[FF + f] + red[2 * FF + f] + red[3 * FF + f];
        atomicAdd(&sumexp[b * FF + f], tot);
    }
}

// ---------------- Kernel 2: fused conv+BN+softmax+pos -> GEMM -> sigmoid -> shift --
// One block per (b, 128-t tile). Recompute conv into As[f][t] (stride 132), then
// iterate all 32 l-tiles: stage Bs (32x128 half-K), 8x8 fp32 FMA, sigmoid epilogue,
// block-reduce over t, atomicAdd into shift[b,l].
__global__ __launch_bounds__(256) void k_main(
        const float* __restrict__ x,  const float* __restrict__ cw,
        const float* __restrict__ cb, const float* __restrict__ gm,
        const float* __restrict__ bt, const float* __restrict__ mn,
        const float* __restrict__ vr, const float* __restrict__ dw,
        const float* __restrict__ db, const float* __restrict__ sumexp,
        float* __restrict__ shift) {
    __shared__ float As[FF * 132];    // 33792 B, As[f][t]
    __shared__ float rest[6736];      // 26944 B, multi-use
    float* xs  = rest;                // 138*8 = 1104 floats   (conv phase)
    float* wsm = rest + 1104;         // 5632 floats           (conv phase)
    float* Bs  = rest;                // 32*128 = 4096 floats  (gemm phase)
    float* red = rest + 4096;         // 128*17 = 2176 floats  (gemm phase)

    const int tid = threadIdx.x;
    const int b  = blockIdx.y;
    const int t0 = blockIdx.x * 128;

    // ---- stage conv weights + x slice [t0-5, t0+132] ----
    for (int i = tid; i < KW * CC * FF; i += 256) wsm[i] = cw[i];
    for (int i = tid; i < (128 + KW - 1) * CC; i += 256) {
        int row = i / CC, c = i % CC;
        int t = t0 - (KW / 2) + row;
        xs[i] = (t >= 0 && t < TT) ? x[((size_t)b * TT + t) * CC + c] : 0.0f;
    }
    const int f = tid & 63, tq = tid >> 6;
    const float s  = gm[f] * rsqrtf(vr[f] + 1e-3f);
    const float bb = bt[f] + (cb[f] - mn[f]) * s;
    const float inv_se = 1.0f / sumexp[b * FF + f];
    const float tsf = exp2f(-0.20762050586796017f * (float)(f & ~1)); // log2(1e-4)/64
    __syncthreads();

    // ---- conv + BN + exp + /sumexp + posenc -> As[f][t] ----
    for (int tt = tq; tt < 128; tt += 4) {
        float acc = 0.f;
#pragma unroll
        for (int k = 0; k < KW; ++k) {
#pragma unroll
            for (int c = 0; c < CC; ++c)
                acc = fmaf(xs[(tt + k) * CC + c], wsm[(k * CC + c) * FF + f], acc);
        }
        float e = __expf(fmaf(acc, s, bb));
        float ang = (float)(t0 + tt) * tsf;
        float p = (f & 1) ? cosf(ang) : sinf(ang);
        As[f * 132 + tt] = fmaf(e, inv_se, p);
    }
    // (next __syncthreads inside the lt loop makes As visible & retires xs/wsm)

    const int tx = tid & 15, ty = tid >> 4;
    const float4* As4 = reinterpret_cast<const float4*>(As);
    const float4* Bs4 = reinterpret_cast<const float4*>(Bs);

    for (int lt = 0; lt < 32; ++lt) {
        const int l0 = lt * 128;
        float acc[8][8];
#pragma unroll
        for (int i = 0; i < 8; ++i)
#pragma unroll
            for (int j = 0; j < 8; ++j) acc[i][j] = 0.f;

        for (int kk = 0; kk < FF; kk += 32) {
            __syncthreads();   // prior consumers of Bs/red done; (lt=0,kk=0): As ready
            {
                const int r = tid >> 5;            // 0..7
                const int col = (tid & 31) * 4;
#pragma unroll
                for (int rr = r; rr < 32; rr += 8) {
                    *reinterpret_cast<float4*>(&Bs[rr * 128 + col]) =
                        *reinterpret_cast<const float4*>(
                            dw + (size_t)(kk + rr) * LL + l0 + col);
                }
            }
            __syncthreads();
#pragma unroll
            for (int k = 0; k < 32; ++k) {
                float4 a0 = As4[(kk + k) * 33 + ty * 2];
                float4 a1 = As4[(kk + k) * 33 + ty * 2 + 1];
                float4 b0 = Bs4[k * 32 + tx * 2];
                float4 b1 = Bs4[k * 32 + tx * 2 + 1];
                float av[8] = {a0.x, a0.y, a0.z, a0.w, a1.x, a1.y, a1.z, a1.w};
                float bv[8] = {b0.x, b0.y, b0.z, b0.w, b1.x, b1.y, b1.z, b1.w};
#pragma unroll
                for (int i = 0; i < 8; ++i)
#pragma unroll
                    for (int j = 0; j < 8; ++j)
                        acc[i][j] = fmaf(av[i], bv[j], acc[i][j]);
            }
        }

        // epilogue: d = 2*sigmoid(z)-1, partial sums over this thread's 8 t values
        float p[8];
#pragma unroll
        for (int j = 0; j < 8; ++j) {
            const float dbv = db[l0 + tx * 8 + j];
            p[j] = 0.f;
#pragma unroll
            for (int i = 0; i < 8; ++i) {
                float z = acc[i][j] + dbv;
                float sg = 1.0f / (1.0f + __expf(-z));
                p[j] += fmaf(2.0f, sg, -1.0f);
            }
        }
        __syncthreads();   // all compute done before red overwrite
#pragma unroll
        for (int j = 0; j < 8; ++j) red[(tx * 8 + j) * 17 + ty] = p[j];
        __syncthreads();
        if (tid < 128) {
            float sum = 0.f;
#pragma unroll
            for (int q = 0; q < 16; ++q) sum += red[tid * 17 + q];
            atomicAdd(&shift[(size_t)b * LL + l0 + tid], sum);
        }
        // next lt's first __syncthreads protects red reads vs future writes
    }
}

// ---------------- Kernel 3: truncated Gaussian warp ------------------------------
__global__ __launch_bounds__(256) void k_warp(
        const float* __restrict__ shift, const float* __restrict__ x,
        float* __restrict__ out) {
    const int idx = blockIdx.x * 256 + threadIdx.x;  // = b*L + l
    const int l = idx & (LL - 1);
    const int b = idx >> 12;
    const float sh = shift[idx];
    const float scale = (float)TT / (float)LL;
    const float center = ((float)(l + 1) + sh) * scale;
    const float R = 7.0f;
    int tlo = (int)ceilf(center - 1.0f - R);
    int thi = (int)floorf(center - 1.0f + R);
    if (tlo < 0) tlo = 0;
    if (thi > TT - 1) thi = TT - 1;
    float acc[CC];
#pragma unroll
    for (int c = 0; c < CC; ++c) acc[c] = 0.f;
    const float inv_amp = (float)(1.0 / 1.772637204826652);
    for (int t = tlo; t <= thi; ++t) {
        float d = (float)(t + 1) - center;
        float w = __expf(-d * d) * inv_amp;   // WIDTH = 1
        const float4 x0 = *reinterpret_cast<const float4*>(x + ((size_t)b * TT + t) * CC);
        const float4 x1 = *reinterpret_cast<const float4*>(x + ((size_t)b * TT + t) * CC + 4);
        acc[0] = fmaf(w, x0.x, acc[0]);
        acc[1] = fmaf(w, x0.y, acc[1]);
        acc[2] = fmaf(w, x0.z, acc[2]);
        acc[3] = fmaf(w, x0.w, acc[3]);
        acc[4] = fmaf(w, x1.x, acc[4]);
        acc[5] = fmaf(w, x1.y, acc[5]);
        acc[6] = fmaf(w, x1.z, acc[6]);
        acc[7] = fmaf(w, x1.w, acc[7]);
    }
    float* o = out + (size_t)idx * CC;
    *reinterpret_cast<float4*>(o)     = make_float4(acc[0], acc[1], acc[2], acc[3]);
    *reinterpret_cast<float4*>(o + 4) = make_float4(acc[4], acc[5], acc[6], acc[7]);
}

extern "C" void kernel_launch(void* const* d_in, const int* in_sizes, int n_in,
                              void* d_out, int out_size, void* d_ws, size_t ws_size,
                              hipStream_t stream) {
    const float* x  = (const float*)d_in[0];
    const float* cw = (const float*)d_in[1];
    const float* cb = (const float*)d_in[2];
    const float* gm = (const float*)d_in[3];
    const float* bt = (const float*)d_in[4];
    const float* mn = (const float*)d_in[5];
    const float* vr = (const float*)d_in[6];
    const float* dw = (const float*)d_in[7];
    const float* db = (const float*)d_in[8];

    float* sumexp = (float*)d_ws;                 // B*F floats   (4 KB)
    float* shift  = sumexp + BB * FF;             // B*L floats   (256 KB)

    hipMemsetAsync(sumexp, 0, (size_t)(BB * FF + BB * LL) * sizeof(float), stream);

    k_sumexp<<<BB * (TT / 64), 256, 0, stream>>>(x, cw, cb, gm, bt, mn, vr, sumexp);
    k_main<<<dim3(TT / 128, BB), 256, 0, stream>>>(x, cw, cb, gm, bt, mn, vr,
                                                   dw, db, sumexp, shift);
    k_warp<<<(BB * LL) / 256, 256, 0, stream>>>(shift, x, (float*)d_out);
}

// Round 4
// 393.787 us; speedup vs baseline: 2.3401x; 2.3401x over previous
//
#include <hip/hip_runtime.h>
#include <stdint.h>

#define BB 16
#define TT 4096
#define CC 8
#define FF 64
#define KW 11
#define LL 4096

typedef __attribute__((ext_vector_type(8))) short short8;
typedef __attribute__((ext_vector_type(16))) float floatx16;

__device__ __forceinline__ unsigned short f2b(float f) {
    union { float f; uint32_t i; } v; v.f = f;
    uint32_t x = v.i;
    return (unsigned short)((x + 0x7fffu + ((x >> 16) & 1u)) >> 16);  // RNE
}
__device__ __forceinline__ float b2f(unsigned short u) {
    union { uint32_t i; float f; } v; v.i = ((uint32_t)u) << 16; return v.f;
}
// pack fp32 -> (hi bf16 in low16) | (residual-lo bf16 in high16)
__device__ __forceinline__ uint32_t packsplit(float v) {
    unsigned short hi = f2b(v);
    unsigned short lo = f2b(v - b2f(hi));
    return (uint32_t)hi | ((uint32_t)lo << 16);
}
__device__ __forceinline__ short8 mk8(uint32_t a, uint32_t b, uint32_t c, uint32_t d) {
    union { uint32_t u[4]; short8 s; } r;
    r.u[0] = a; r.u[1] = b; r.u[2] = c; r.u[3] = d; return r.s;
}
__device__ __forceinline__ short8 mk_hi(uint4 q0, uint4 q1) {
    return mk8((q0.x & 0xffffu) | (q0.y << 16), (q0.z & 0xffffu) | (q0.w << 16),
               (q1.x & 0xffffu) | (q1.y << 16), (q1.z & 0xffffu) | (q1.w << 16));
}
__device__ __forceinline__ short8 mk_lo(uint4 q0, uint4 q1) {
    return mk8((q0.x >> 16) | (q0.y & 0xffff0000u), (q0.z >> 16) | (q0.w & 0xffff0000u),
               (q1.x >> 16) | (q1.y & 0xffff0000u), (q1.z >> 16) | (q1.w & 0xffff0000u));
}

// ---------------- Kernel 0: W fp32 [64][4096] -> packed hi/lo bf16, transposed [l][k]
__global__ __launch_bounds__(256) void k_split(
        const float* __restrict__ dw, uint32_t* __restrict__ Wt) {
    const int idx = blockIdx.x * 256 + threadIdx.x;   // 262144
    const int k = idx >> 12, l = idx & (LL - 1);
    Wt[l * 64 + k] = packsplit(dw[idx]);
}

// ---------------- Kernel 1: conv1d + BN + exp -> sumexp[b,f] ----------------------
__global__ __launch_bounds__(256) void k_sumexp(
        const float* __restrict__ x, const float* __restrict__ cw,
        const float* __restrict__ cb, const float* __restrict__ gm,
        const float* __restrict__ bt, const float* __restrict__ mn,
        const float* __restrict__ vr, float* __restrict__ sumexp) {
    __shared__ float wsm[KW * CC * FF];
    __shared__ float xs[(64 + KW - 1) * CC];
    __shared__ float red[4 * FF];
    const int tid = threadIdx.x;
    const int b  = blockIdx.x / (TT / 64);
    const int t0 = (blockIdx.x % (TT / 64)) * 64;

    for (int i = tid; i < KW * CC * FF; i += 256) wsm[i] = cw[i];
    for (int i = tid; i < (64 + KW - 1) * CC; i += 256) {
        int row = i / CC, c = i % CC;
        int t = t0 - (KW / 2) + row;
        xs[i] = (t >= 0 && t < TT) ? x[((size_t)b * TT + t) * CC + c] : 0.0f;
    }
    const int f = tid & 63, ts = tid >> 6;
    const float s  = gm[f] * rsqrtf(vr[f] + 1e-3f);
    const float bb = bt[f] + (cb[f] - mn[f]) * s;
    __syncthreads();

    float esum = 0.f;
    for (int tt = ts; tt < 64; tt += 4) {
        float acc = 0.f;
#pragma unroll
        for (int k = 0; k < KW; ++k)
#pragma unroll
            for (int c = 0; c < CC; ++c)
                acc = fmaf(xs[(tt + k) * CC + c], wsm[(k * CC + c) * FF + f], acc);
        esum += __expf(fmaf(acc, s, bb));
    }
    red[ts * FF + f] = esum;
    __syncthreads();
    if (ts == 0) {
        float tot = red[f] + red[FF + f] + red[2 * FF + f] + red[3 * FF + f];
        atomicAdd(&sumexp[b * FF + f], tot);
    }
}

// ---------------- Kernel 2: conv+softmax+pos -> split-bf16 MFMA GEMM -> sigma-sum --
// Block = (b, 128-t tile). Asp[t][f] packed hi/lo bf16 of h2. Wave w owns l-range
// lt*128 + w*32; A-frags = Wt from global (L2-hot), B-frags = Asp ds_read_b128.
// acc (32l x 32t) -> sigmoid -> fold over t, butterfly over 32 cols, atomicAdd.
__global__ __launch_bounds__(256) void k_main(
        const float* __restrict__ x,  const float* __restrict__ cw,
        const float* __restrict__ cb, const float* __restrict__ gm,
        const float* __restrict__ bt, const float* __restrict__ mn,
        const float* __restrict__ vr, const uint32_t* __restrict__ Wt,
        const float* __restrict__ db, const float* __restrict__ sumexp,
        float* __restrict__ shiftsum) {
    __shared__ uint32_t Asp[128 * 68];   // 34816 B
    __shared__ float scratch[6736];      // 26944 B (conv phase only)
    __shared__ float dbs[LL];            // 16384 B
    float* xs  = scratch;                // 1104 floats
    float* wsm = scratch + 1104;         // 5632 floats

    const int tid = threadIdx.x;
    const int b  = blockIdx.y;
    const int t0 = blockIdx.x * 128;

    for (int i = tid; i < LL; i += 256) dbs[i] = db[i];
    for (int i = tid; i < KW * CC * FF; i += 256) wsm[i] = cw[i];
    for (int i = tid; i < (128 + KW - 1) * CC; i += 256) {
        int row = i / CC, c = i % CC;
        int t = t0 - (KW / 2) + row;
        xs[i] = (t >= 0 && t < TT) ? x[((size_t)b * TT + t) * CC + c] : 0.0f;
    }
    const int f = tid & 63, tq = tid >> 6;
    const float s  = gm[f] * rsqrtf(vr[f] + 1e-3f);
    const float bbv = bt[f] + (cb[f] - mn[f]) * s;
    const float inv_se = 1.0f / sumexp[b * FF + f];
    const float tsf = exp2f(-0.20762050586796017f * (float)(f & ~1));
    __syncthreads();

    for (int tt = tq; tt < 128; tt += 4) {
        float acc = 0.f;
#pragma unroll
        for (int k = 0; k < KW; ++k)
#pragma unroll
            for (int c = 0; c < CC; ++c)
                acc = fmaf(xs[(tt + k) * CC + c], wsm[(k * CC + c) * FF + f], acc);
        float e = __expf(fmaf(acc, s, bbv));
        float ang = (float)(t0 + tt) * tsf;
        float p = (f & 1) ? cosf(ang) : sinf(ang);
        Asp[tt * 68 + f] = packsplit(fmaf(e, inv_se, p));
    }
    __syncthreads();
    // ---- main loop: no barriers from here on ----
    const int lane = tid & 63;
    const int wv   = tid >> 6;
    const int half = lane >> 5;
    const int ln31 = lane & 31;

    for (int lt = 0; lt < 32; ++lt) {
        const int lbase = lt * 128 + wv * 32;
        // A-frags: W for this wave's 32 l, all K=64, straight from global (L2-hot)
        const uint32_t* wp = Wt + (size_t)(lbase + ln31) * 64 + half * 8;
        uint4 wr[8];
#pragma unroll
        for (int kf = 0; kf < 4; ++kf) {
            wr[kf * 2]     = *reinterpret_cast<const uint4*>(wp + kf * 16);
            wr[kf * 2 + 1] = *reinterpret_cast<const uint4*>(wp + kf * 16 + 4);
        }
        short8 Whi[4], Wlo[4];
#pragma unroll
        for (int kf = 0; kf < 4; ++kf) {
            Whi[kf] = mk_hi(wr[kf * 2], wr[kf * 2 + 1]);
            Wlo[kf] = mk_lo(wr[kf * 2], wr[kf * 2 + 1]);
        }
        float dbv[16], sumsig[16];
#pragma unroll
        for (int r = 0; r < 16; ++r) {
            dbv[r] = dbs[lbase + 4 * half + (r & 3) + 8 * (r >> 2)];
            sumsig[r] = 0.f;
        }
        for (int nt = 0; nt < 4; ++nt) {
            floatx16 acc = {0.f, 0.f, 0.f, 0.f, 0.f, 0.f, 0.f, 0.f,
                            0.f, 0.f, 0.f, 0.f, 0.f, 0.f, 0.f, 0.f};
            const uint32_t* ap = Asp + (nt * 32 + ln31) * 68 + half * 8;
#pragma unroll
            for (int kf = 0; kf < 4; ++kf) {
                uint4 q0 = *reinterpret_cast<const uint4*>(ap + kf * 16);
                uint4 q1 = *reinterpret_cast<const uint4*>(ap + kf * 16 + 4);
                short8 Bhi = mk_hi(q0, q1);
                short8 Blo = mk_lo(q0, q1);
                acc = __builtin_amdgcn_mfma_f32_32x32x16_bf16(Whi[kf], Bhi, acc, 0, 0, 0);
                acc = __builtin_amdgcn_mfma_f32_32x32x16_bf16(Whi[kf], Blo, acc, 0, 0, 0);
                acc = __builtin_amdgcn_mfma_f32_32x32x16_bf16(Wlo[kf], Bhi, acc, 0, 0, 0);
            }
#pragma unroll
            for (int r = 0; r < 16; ++r) {
                float z = acc[r] + dbv[r];
                float e = __expf(-z);
                sumsig[r] += __builtin_amdgcn_rcpf(1.0f + e);   // sigma(z)
            }
        }
#pragma unroll
        for (int r = 0; r < 16; ++r) {
            float v = sumsig[r];
            v += __shfl_xor(v, 1, 32);
            v += __shfl_xor(v, 2, 32);
            v += __shfl_xor(v, 4, 32);
            v += __shfl_xor(v, 8, 32);
            v += __shfl_xor(v, 16, 32);
            sumsig[r] = v;
        }
        if (ln31 == 0) {
            float* dst = shiftsum + (size_t)b * LL + lbase + 4 * half;
#pragma unroll
            for (int r = 0; r < 16; ++r)
                atomicAdd(dst + (r & 3) + 8 * (r >> 2), sumsig[r]);
        }
    }
}

// ---------------- Kernel 3: truncated Gaussian warp (shift = 2*S - T) -------------
__global__ __launch_bounds__(256) void k_warp(
        const float* __restrict__ shiftsum, const float* __restrict__ x,
        float* __restrict__ out) {
    const int idx = blockIdx.x * 256 + threadIdx.x;  // = b*L + l
    const int l = idx & (LL - 1);
    const int b = idx >> 12;
    const float sh = fmaf(2.0f, shiftsum[idx], -(float)TT);
    const float scale = (float)TT / (float)LL;
    const float center = ((float)(l + 1) + sh) * scale;
    const float R = 7.0f;
    int tlo = (int)ceilf(center - 1.0f - R);
    int thi = (int)floorf(center - 1.0f + R);
    if (tlo < 0) tlo = 0;
    if (thi > TT - 1) thi = TT - 1;
    float acc[CC];
#pragma unroll
    for (int c = 0; c < CC; ++c) acc[c] = 0.f;
    const float inv_amp = (float)(1.0 / 1.772637204826652);
    for (int t = tlo; t <= thi; ++t) {
        float d = (float)(t + 1) - center;
        float w = __expf(-d * d) * inv_amp;   // WIDTH = 1
        const float4 x0 = *reinterpret_cast<const float4*>(x + ((size_t)b * TT + t) * CC);
        const float4 x1 = *reinterpret_cast<const float4*>(x + ((size_t)b * TT + t) * CC + 4);
        acc[0] = fmaf(w, x0.x, acc[0]);
        acc[1] = fmaf(w, x0.y, acc[1]);
        acc[2] = fmaf(w, x0.z, acc[2]);
        acc[3] = fmaf(w, x0.w, acc[3]);
        acc[4] = fmaf(w, x1.x, acc[4]);
        acc[5] = fmaf(w, x1.y, acc[5]);
        acc[6] = fmaf(w, x1.z, acc[6]);
        acc[7] = fmaf(w, x1.w, acc[7]);
    }
    float* o = out + (size_t)idx * CC;
    *reinterpret_cast<float4*>(o)     = make_float4(acc[0], acc[1], acc[2], acc[3]);
    *reinterpret_cast<float4*>(o + 4) = make_float4(acc[4], acc[5], acc[6], acc[7]);
}

extern "C" void kernel_launch(void* const* d_in, const int* in_sizes, int n_in,
                              void* d_out, int out_size, void* d_ws, size_t ws_size,
                              hipStream_t stream) {
    const float* x  = (const float*)d_in[0];
    const float* cw = (const float*)d_in[1];
    const float* cb = (const float*)d_in[2];
    const float* gm = (const float*)d_in[3];
    const float* bt = (const float*)d_in[4];
    const float* mn = (const float*)d_in[5];
    const float* vr = (const float*)d_in[6];
    const float* dw = (const float*)d_in[7];
    const float* db = (const float*)d_in[8];

    float* sumexp    = (float*)d_ws;                       // 1024 floats
    float* shiftsum  = sumexp + BB * FF;                   // 65536 floats
    uint32_t* Wt     = (uint32_t*)(shiftsum + BB * LL);    // 262144 dwords (1 MB)

    hipMemsetAsync(sumexp, 0, (size_t)(BB * FF + BB * LL) * sizeof(float), stream);

    k_split<<<(FF * LL) / 256, 256, 0, stream>>>(dw, Wt);
    k_sumexp<<<BB * (TT / 64), 256, 0, stream>>>(x, cw, cb, gm, bt, mn, vr, sumexp);
    k_main<<<dim3(TT / 128, BB), 256, 0, stream>>>(x, cw, cb, gm, bt, mn, vr,
                                                   Wt, db, sumexp, shiftsum);
    k_warp<<<(BB * LL) / 256, 256, 0, stream>>>(shiftsum, x, (float*)d_out);
}